// Round 1
// baseline (230.331 us; speedup 1.0000x reference)
//
#include <hip/hip_runtime.h>
#include <stdint.h>

#define B_ 4
#define S_ 2048
#define D_ 1024
#define H_ 16
#define DH_ 64
#define M_TOT (B_*S_)   // 8192
#define N1_ (3*D_)      // 3072
#define K_ D_           // 1024
#define NCH 8           // s-chunks for attention score partials

typedef __bf16 bf16_8 __attribute__((ext_vector_type(8)));
typedef float  f32x4  __attribute__((ext_vector_type(4)));
typedef unsigned short u16;

typedef __attribute__((address_space(1))) const void* gas_t;
typedef __attribute__((address_space(3))) void*       las_t;

__device__ __forceinline__ unsigned short f2bf(float f) {
    union { float f; unsigned u; } v; v.f = f;
    unsigned r = v.u + 0x7FFFu + ((v.u >> 16) & 1u);
    return (unsigned short)(r >> 16);
}

__device__ __forceinline__ void async_ld16(const void* g, void* l) {
    __builtin_amdgcn_global_load_lds((gas_t)g, (las_t)l, 16, 0, 0);
}

// ---------------- cast fp32 -> bf16 (X, W1, W2) ----------------
__global__ __launch_bounds__(256)
void cast_kernel(const float* __restrict__ X, const float* __restrict__ W1,
                 const float* __restrict__ W2, unsigned short* __restrict__ Xb,
                 unsigned short* __restrict__ W1b, unsigned short* __restrict__ W2b) {
    const int nX  = (M_TOT * K_) / 4;   // 2097152
    const int nW1 = (N1_ * K_) / 4;     // 786432
    int i = blockIdx.x * 256 + threadIdx.x;   // float4 index
    const float4* src; unsigned short* dst; int j;
    if (i < nX)            { src = (const float4*)X;  dst = Xb;  j = i; }
    else if (i < nX + nW1) { src = (const float4*)W1; dst = W1b; j = i - nX; }
    else                   { src = (const float4*)W2; dst = W2b; j = i - nX - nW1; }
    float4 v = src[j];
    ushort4 o;
    o.x = f2bf(v.x); o.y = f2bf(v.y); o.z = f2bf(v.z); o.w = f2bf(v.w);
    ((ushort4*)dst)[j] = o;
}

// ---------------- gemm_bt2: 256x256 tile, 8-wave, 8-phase counted-vmcnt ----------------
// C[M,N] = A[M,K] * B[N,K]^T + bias.
// LDS: 2 buffers (even/odd K-tile) x (A 256x64 + B 256x64) bf16 = 128 KiB.
// LDS row order is wave-permuted so each half-tile is one contiguous 8KB region:
//   A: rho = mh*128 + wr*64 + r   <-> global row  wr*128 + mh*64 + r
//   B: rho = nh*128 + wc*32 + r   <-> global row  wc*64  + nh*32 + r
// Within a row (64 bf16 = 8 x 16B blocks), source k-block = blk ^ (rho&7)
// (linear LDS dest + pre-swizzled global source; reads XOR the same way) ->
// conflict-free ds_read_b128 (16-lane groups: 8 blocks x 2-way).
// Schedule per iteration (2 K-tiles E=2i in buf0, O=2i+1 in buf1), per phase:
//   {ds_read subtile ; issue 1 half-tile global_load_lds} barrier lgkmcnt(0)
//   setprio(1) 16xMFMA setprio(0) [vmcnt(6) @P4/P8] barrier
// Prefetch slots follow half-tile deadness: A-lo dies P1 -> staged P2, etc.
// vmcnt(6) = 3 half-tiles in flight; never drained to 0 in the main loop.

#define LDA_H(AS, MH, AF) do {                                                     \
  _Pragma("unroll") for (int m_ = 0; m_ < 4; m_++)                                 \
  _Pragma("unroll") for (int ks_ = 0; ks_ < 2; ks_++) {                            \
    const int rho_ = (MH)*128 + wr*64 + m_*16 + lrow;                              \
    AF[m_][ks_] = *(const bf16_8*)((const u16*)(AS) + rho_*64 +                    \
                                   (((ks_*4+lq) ^ (lrow&7)) << 3)); } } while (0)

#define LDB_H(BS, NH, BF) do {                                                     \
  _Pragma("unroll") for (int n_ = 0; n_ < 2; n_++)                                 \
  _Pragma("unroll") for (int ks_ = 0; ks_ < 2; ks_++) {                            \
    const int rho_ = (NH)*128 + wc*32 + n_*16 + lrow;                              \
    BF[n_][ks_] = *(const bf16_8*)((const u16*)(BS) + rho_*64 +                    \
                                   (((ks_*4+lq) ^ (lrow&7)) << 3)); } } while (0)

#define MMA_Q(MH, NH, AF, BF) do {                                                 \
    __builtin_amdgcn_s_setprio(1);                                                 \
    _Pragma("unroll") for (int ks_ = 0; ks_ < 2; ks_++)                            \
    _Pragma("unroll") for (int m_ = 0; m_ < 4; m_++)                               \
    _Pragma("unroll") for (int n_ = 0; n_ < 2; n_++)                               \
        acc[(MH)*4+m_][(NH)*2+n_] = __builtin_amdgcn_mfma_f32_16x16x32_bf16(       \
            AF[m_][ks_], BF[n_][ks_], acc[(MH)*4+m_][(NH)*2+n_], 0, 0, 0);         \
    __builtin_amdgcn_s_setprio(0);                                                 \
  } while (0)

#define BAR()      __builtin_amdgcn_s_barrier()
#define WAIT_LGKM() asm volatile("s_waitcnt lgkmcnt(0)" ::: "memory")

template<int N, int NBX, int KK, bool OUT_BF16>
__global__ __launch_bounds__(512, 2)
void gemm_bt2(const u16* __restrict__ A, const u16* __restrict__ Bm,
              const float* __restrict__ bias, void* __restrict__ C) {
    __shared__ u16 As[2][256 * 64];
    __shared__ u16 Bs[2][256 * 64];

    const int t    = threadIdx.x;
    const int wid  = t >> 6;
    const int lane = t & 63;
    const int lrow = lane & 15;
    const int lq   = lane >> 4;
    const int wr   = wid >> 2;   // 0..1  (M wave row)
    const int wc   = wid & 3;    // 0..3  (N wave col)

    // XCD-aware swizzle: each XCD owns a contiguous M-stripe, bx fastest.
    const int lid  = blockIdx.y * NBX + blockIdx.x;
    const int xcd  = lid & 7;
    const int slot = lid >> 3;
    const int by   = xcd * (gridDim.y >> 3) + slot / NBX;
    const int bx   = slot % NBX;
    const int m0   = by * 256;
    const int n0   = bx * 256;

    const u16* Ab = A  + (size_t)m0 * KK;
    const u16* Bb = Bm + (size_t)n0 * KK;

    f32x4 acc[8][4] = {};

    // Stage one half-tile (2 chunks of 64 LDS rows, 1 load/thread/chunk).
    auto STG = [&](const u16* __restrict__ G, char* lds, int half, int k0, bool isA) {
#pragma unroll
        for (int cc = 0; cc < 2; cc++) {
            const int rho = half * 128 + cc * 64 + (t >> 3);
            const int blk = t & 7;
            const int g   = isA ? (((rho >> 6) & 1) * 128 + ((rho >> 7) & 1) * 64 + (rho & 63))
                                : (((rho >> 5) & 3) * 64  + ((rho >> 7) & 1) * 32 + (rho & 31));
            async_ld16(G + (size_t)g * KK + k0 + ((blk ^ (rho & 7)) << 3),
                       lds + rho * 128 + blk * 16);
        }
    };

    char* as0 = (char*)&As[0][0]; char* as1 = (char*)&As[1][0];
    char* bs0 = (char*)&Bs[0][0]; char* bs1 = (char*)&Bs[1][0];

    // prologue: tile0 fully into buf0; tile1's first 3 halves into buf1
    STG(Ab, as0, 0, 0,  true);
    STG(Bb, bs0, 0, 0,  false);
    STG(Bb, bs0, 1, 0,  false);
    STG(Ab, as0, 1, 0,  true);
    STG(Ab, as1, 0, 64, true);
    STG(Bb, bs1, 0, 64, false);
    STG(Bb, bs1, 1, 64, false);
    asm volatile("s_waitcnt vmcnt(6)" ::: "memory");   // tile0 landed
    BAR();

    bf16_8 af[4][2], blo[2][2], bhi[2][2];

    constexpr int NT = KK / 64;
    constexpr int NI = NT / 2;

    for (int i = 0; i < NI; ++i) {
        const bool pf = (i < NI - 1);
        const int kE = (2 * i + 2) * 64;
        const int kO = (2 * i + 3) * 64;

        // ---- P1: read E.A-lo + E.B-lo ; stage O.A-hi ; mma quad(0,0)
        LDA_H(as0, 0, af);
        LDB_H(bs0, 0, blo);
        STG(Ab, as1, 1, (2 * i + 1) * 64, true);
        BAR(); WAIT_LGKM();
        MMA_Q(0, 0, af, blo);
        BAR();
        // ---- P2: read E.B-hi ; stage E'.A-lo ; mma quad(0,1)
        LDB_H(bs0, 1, bhi);
        if (pf) STG(Ab, as0, 0, kE, true);
        BAR(); WAIT_LGKM();
        MMA_Q(0, 1, af, bhi);
        BAR();
        // ---- P3: read E.A-hi ; stage E'.B-lo ; mma quad(1,1)
        LDA_H(as0, 1, af);
        if (pf) STG(Bb, bs0, 0, kE, false);
        BAR(); WAIT_LGKM();
        MMA_Q(1, 1, af, bhi);
        BAR();
        // ---- P4: stage E'.B-hi ; mma quad(1,0) ; vmcnt -> tile O landed
        if (pf) STG(Bb, bs0, 1, kE, false);
        BAR();
        MMA_Q(1, 0, af, blo);
        if (pf) { asm volatile("s_waitcnt vmcnt(6)" ::: "memory"); }
        else    { asm volatile("s_waitcnt vmcnt(0)" ::: "memory"); }
        BAR();
        // ---- P5: read O.A-lo + O.B-lo ; stage E'.A-hi ; mma quad(0,0)
        LDA_H(as1, 0, af);
        LDB_H(bs1, 0, blo);
        if (pf) STG(Ab, as0, 1, kE, true);
        BAR(); WAIT_LGKM();
        MMA_Q(0, 0, af, blo);
        BAR();
        // ---- P6: read O.B-hi ; stage O'.A-lo ; mma quad(0,1)
        LDB_H(bs1, 1, bhi);
        if (pf) STG(Ab, as1, 0, kO, true);
        BAR(); WAIT_LGKM();
        MMA_Q(0, 1, af, bhi);
        BAR();
        // ---- P7: read O.A-hi ; stage O'.B-lo ; mma quad(1,1)
        LDA_H(as1, 1, af);
        if (pf) STG(Bb, bs1, 0, kO, false);
        BAR(); WAIT_LGKM();
        MMA_Q(1, 1, af, bhi);
        BAR();
        // ---- P8: stage O'.B-hi ; mma quad(1,0) ; vmcnt -> tile E' landed
        if (pf) STG(Bb, bs1, 1, kO, false);
        BAR();
        MMA_Q(1, 0, af, blo);
        if (pf) asm volatile("s_waitcnt vmcnt(6)" ::: "memory");
        BAR();
    }

    // epilogue: row = m0 + wr*128 + mt*16 + lq*4 + i, col = n0 + wc*64 + nt*16 + lrow
#pragma unroll
    for (int nt = 0; nt < 4; nt++) {
        const int col = n0 + wc * 64 + nt * 16 + lrow;
        const float bv = bias[col];
#pragma unroll
        for (int mt = 0; mt < 8; mt++) {
            const int row = m0 + wr * 128 + mt * 16 + lq * 4;
            f32x4 a = acc[mt][nt];
            if (OUT_BF16) {
                u16* Cp = (u16*)C;
#pragma unroll
                for (int i2 = 0; i2 < 4; i2++)
                    Cp[(size_t)(row + i2) * N + col] = f2bf(a[i2] + bv);
            } else {
                float* Cp = (float*)C;
#pragma unroll
                for (int i2 = 0; i2 < 4; i2++)
                    Cp[(size_t)(row + i2) * N + col] = a[i2] + bv;
            }
        }
    }
}

// ---------------- attention, stage 1: partial scores ----------------
__global__ __launch_bounds__(256)
void attn_scores(const unsigned short* __restrict__ Y, float* __restrict__ Scp) {
    __shared__ unsigned short Qs[64 * 72];
    __shared__ unsigned short Ks[64 * 72];
    const int bh = blockIdx.x, ch = blockIdx.y;
    const int b = bh >> 4, h = bh & 15;
    const size_t ybase = (size_t)b * S_ * 3072;
    const int qoff = h * 64, koff = D_ + h * 64;
    const int t = threadIdx.x, wid = t >> 6, lane = t & 63;
    const int lrow = lane & 15, lq = lane >> 4;

    f32x4 acc[4] = {};
    const int sbeg = ch * (S_ / NCH);
    for (int s0 = sbeg; s0 < sbeg + S_ / NCH; s0 += 64) {
#pragma unroll
        for (int p = 0; p < 4; p++) {
            int idx = p * 256 + t;            // 0..1023
            int r = idx >> 4, cg = (idx & 15) * 4;
            const size_t gb = ybase + (size_t)(s0 + r) * 3072;
            ushort4 q4 = *(const ushort4*)(Y + gb + qoff + cg);
            ushort4 k4 = *(const ushort4*)(Y + gb + koff + cg);
            Qs[(cg + 0) * 72 + r] = q4.x; Qs[(cg + 1) * 72 + r] = q4.y;
            Qs[(cg + 2) * 72 + r] = q4.z; Qs[(cg + 3) * 72 + r] = q4.w;
            Ks[(cg + 0) * 72 + r] = k4.x; Ks[(cg + 1) * 72 + r] = k4.y;
            Ks[(cg + 2) * 72 + r] = k4.z; Ks[(cg + 3) * 72 + r] = k4.w;
        }
        __syncthreads();
#pragma unroll
        for (int ks = 0; ks < 2; ks++) {
            bf16_8 aq = *(const bf16_8*)(Qs + (wid * 16 + lrow) * 72 + ks * 32 + lq * 8);
#pragma unroll
            for (int nt = 0; nt < 4; nt++) {
                bf16_8 bk = *(const bf16_8*)(Ks + (nt * 16 + lrow) * 72 + ks * 32 + lq * 8);
                acc[nt] = __builtin_amdgcn_mfma_f32_16x16x32_bf16(aq, bk, acc[nt], 0, 0, 0);
            }
        }
        __syncthreads();
    }

    float* out = Scp + (size_t)(bh * NCH + ch) * 64 * 64;
#pragma unroll
    for (int nt = 0; nt < 4; nt++)
#pragma unroll
        for (int i = 0; i < 4; i++)
            out[(wid * 16 + lq * 4 + i) * 64 + nt * 16 + lrow] = acc[nt][i];
}

// ---------------- attention, stage 2: reduce partials + softmax ----------------
__global__ __launch_bounds__(256)
void attn_softmax(const float* __restrict__ Scp, unsigned short* __restrict__ Wb) {
    const int bh = blockIdx.x;
    const int t = threadIdx.x;
    const int d = t >> 2, q = t & 3;
    float s[16] = {};
#pragma unroll
    for (int c = 0; c < NCH; c++) {
        const float4* p = (const float4*)(Scp + ((size_t)(bh * NCH + c) * 64 + d) * 64 + q * 16);
#pragma unroll
        for (int j = 0; j < 4; j++) {
            float4 v = p[j];
            s[j*4+0] += v.x; s[j*4+1] += v.y; s[j*4+2] += v.z; s[j*4+3] += v.w;
        }
    }
    const float scale = 0.022097086912079608f;  // 1/sqrt(2048)
    float m = -3.0e38f;
#pragma unroll
    for (int i = 0; i < 16; i++) { s[i] *= scale; m = fmaxf(m, s[i]); }
    m = fmaxf(m, __shfl_xor(m, 1));
    m = fmaxf(m, __shfl_xor(m, 2));
    float sum = 0.f;
#pragma unroll
    for (int i = 0; i < 16; i++) { s[i] = __expf(s[i] - m); sum += s[i]; }
    sum += __shfl_xor(sum, 1);
    sum += __shfl_xor(sum, 2);
    const float inv = 1.0f / sum;
    unsigned short* w = Wb + (size_t)bh * 4096 + d * 64 + q * 16;
    ushort4 o0, o1, o2, o3;
    o0.x=f2bf(s[0]*inv);  o0.y=f2bf(s[1]*inv);  o0.z=f2bf(s[2]*inv);  o0.w=f2bf(s[3]*inv);
    o1.x=f2bf(s[4]*inv);  o1.y=f2bf(s[5]*inv);  o1.z=f2bf(s[6]*inv);  o1.w=f2bf(s[7]*inv);
    o2.x=f2bf(s[8]*inv);  o2.y=f2bf(s[9]*inv);  o2.z=f2bf(s[10]*inv); o2.w=f2bf(s[11]*inv);
    o3.x=f2bf(s[12]*inv); o3.y=f2bf(s[13]*inv); o3.z=f2bf(s[14]*inv); o3.w=f2bf(s[15]*inv);
    ((ushort4*)w)[0]=o0; ((ushort4*)w)[1]=o1; ((ushort4*)w)[2]=o2; ((ushort4*)w)[3]=o3;
}

// ---------------- attention, stage 3: O = w @ V^T ----------------
__global__ __launch_bounds__(256)
void attn_out(const unsigned short* __restrict__ Y, const unsigned short* __restrict__ Wb,
              unsigned short* __restrict__ O) {
    __shared__ unsigned short Ws[64 * 72];
    const int bh = blockIdx.x, sc = blockIdx.y;
    const int b = bh >> 4, h = bh & 15;
    const size_t ybase = (size_t)b * S_ * 3072;
    const int voff = 2 * D_ + h * 64;
    const int t = threadIdx.x, wid = t >> 6, lane = t & 63;
    const int lrow = lane & 15, lq = lane >> 4;

    {
        const int d = t >> 2, q = t & 3;
        const uint4* src = (const uint4*)(Wb + (size_t)bh * 4096 + d * 64 + q * 16);
        uint4* dst = (uint4*)(Ws + d * 72 + q * 16);
        dst[0] = src[0];
        *(uint4*)(Ws + d * 72 + q * 16 + 8) = src[1];
    }
    __syncthreads();

    bf16_8 aw[4][2];
#pragma unroll
    for (int mt = 0; mt < 4; mt++)
#pragma unroll
        for (int ks = 0; ks < 2; ks++)
            aw[mt][ks] = *(const bf16_8*)(Ws + (mt * 16 + lrow) * 72 + ks * 32 + lq * 8);

    const size_t obase = (size_t)b * (H_ * DH_ * S_) + (size_t)h * (DH_ * S_);
    const int s0 = sc * 256 + wid * 64;
    f32x4 o[4][4] = {};
#pragma unroll
    for (int ks = 0; ks < 2; ks++) {
        bf16_8 bv[4];
#pragma unroll
        for (int nt = 0; nt < 4; nt++)
            bv[nt] = *(const bf16_8*)(Y + ybase + (size_t)(s0 + nt * 16 + lrow) * 3072 + voff + ks * 32 + lq * 8);
#pragma unroll
        for (int mt = 0; mt < 4; mt++)
#pragma unroll
            for (int nt = 0; nt < 4; nt++)
                o[mt][nt] = __builtin_amdgcn_mfma_f32_16x16x32_bf16(aw[mt][ks], bv[nt], o[mt][nt], 0, 0, 0);
    }
#pragma unroll
    for (int mt = 0; mt < 4; mt++)
#pragma unroll
        for (int nt = 0; nt < 4; nt++) {
            const int d = mt * 16 + lq * 4;
            const int s = s0 + nt * 16 + lrow;
#pragma unroll
            for (int i = 0; i < 4; i++)
                O[obase + (size_t)(d + i) * S_ + s] = f2bf(o[mt][nt][i]);
        }
}

extern "C" void kernel_launch(void* const* d_in, const int* in_sizes, int n_in,
                              void* d_out, int out_size, void* d_ws, size_t ws_size,
                              hipStream_t stream) {
    const float* X  = (const float*)d_in[0];
    const float* W1 = (const float*)d_in[1];
    const float* b1 = (const float*)d_in[2];
    const float* W2 = (const float*)d_in[3];
    const float* b2 = (const float*)d_in[4];

    char* ws = (char*)d_ws;
    unsigned short* Xb  = (unsigned short*)(ws + 0);                 // 16 MB, dead after GEMM1
    unsigned short* W1b = (unsigned short*)(ws + (16u << 20));       // 6 MB, dead after GEMM1
    unsigned short* W2b = (unsigned short*)(ws + (22u << 20));       // 2 MB
    unsigned short* Yb  = (unsigned short*)(ws + (24u << 20));       // 48 MB
    // after GEMM1, [0,22MB) is free:
    unsigned short* Wb  = (unsigned short*)(ws + 0);                 // 512 KB softmaxed weights
    unsigned short* Ob  = (unsigned short*)(ws + (1u << 20));        // 16 MB attention output
    // d_out (32 MB fp32) is dead until GEMM2 -> use 8 MB of it for score partials
    float* Scp = (float*)d_out;

    cast_kernel<<<12288, 256, 0, stream>>>(X, W1, W2, Xb, W1b, W2b);
    gemm_bt2<N1_, N1_/256, K_, true ><<<dim3(N1_ / 256, M_TOT / 256), 512, 0, stream>>>(Xb, W1b, b1, Yb);
    attn_scores<<<dim3(64, NCH), 256, 0, stream>>>(Yb, Scp);
    attn_softmax<<<64, 256, 0, stream>>>(Scp, Wb);
    attn_out<<<dim3(64, NCH), 256, 0, stream>>>(Yb, Wb, Ob);
    gemm_bt2<D_, D_/256, K_, false><<<dim3(D_ / 256, M_TOT / 256), 512, 0, stream>>>(Ob, W2b, b2, d_out);
}

// Round 2
// 221.935 us; speedup vs baseline: 1.0378x; 1.0378x over previous
//
#include <hip/hip_runtime.h>
#include <stdint.h>

#define B_ 4
#define S_ 2048
#define D_ 1024
#define H_ 16
#define DH_ 64
#define M_TOT (B_*S_)   // 8192
#define N1_ (3*D_)      // 3072
#define K_ D_           // 1024
#define NCH 8           // s-chunks for attention score partials

typedef __bf16 bf16_8 __attribute__((ext_vector_type(8)));
typedef float  f32x4  __attribute__((ext_vector_type(4)));
typedef unsigned short u16;

typedef __attribute__((address_space(1))) const void* gas_t;
typedef __attribute__((address_space(3))) void*       las_t;

__device__ __forceinline__ unsigned short f2bf(float f) {
    union { float f; unsigned u; } v; v.f = f;
    unsigned r = v.u + 0x7FFFu + ((v.u >> 16) & 1u);
    return (unsigned short)(r >> 16);
}

__device__ __forceinline__ void async_ld16(const void* g, void* l) {
    __builtin_amdgcn_global_load_lds((gas_t)g, (las_t)l, 16, 0, 0);
}

// ---------------- cast fp32 -> bf16 (X, W1, W2) ----------------
__global__ __launch_bounds__(256)
void cast_kernel(const float* __restrict__ X, const float* __restrict__ W1,
                 const float* __restrict__ W2, unsigned short* __restrict__ Xb,
                 unsigned short* __restrict__ W1b, unsigned short* __restrict__ W2b) {
    const int nX  = (M_TOT * K_) / 4;   // 2097152
    const int nW1 = (N1_ * K_) / 4;     // 786432
    int i = blockIdx.x * 256 + threadIdx.x;   // float4 index
    const float4* src; unsigned short* dst; int j;
    if (i < nX)            { src = (const float4*)X;  dst = Xb;  j = i; }
    else if (i < nX + nW1) { src = (const float4*)W1; dst = W1b; j = i - nX; }
    else                   { src = (const float4*)W2; dst = W2b; j = i - nX - nW1; }
    float4 v = src[j];
    ushort4 o;
    o.x = f2bf(v.x); o.y = f2bf(v.y); o.z = f2bf(v.z); o.w = f2bf(v.w);
    ((ushort4*)dst)[j] = o;
}

// ---------------- gemm_bt: classic 128x128 tile (used for GEMM2) ----------------
template<int N, int NBX, bool OUT_BF16>
__global__ __launch_bounds__(256)
void gemm_bt(const unsigned short* __restrict__ A,
             const unsigned short* __restrict__ Bm,
             const float* __restrict__ bias,
             void* __restrict__ C, int K) {
    __shared__ unsigned short As[128 * 64];
    __shared__ unsigned short Bs[128 * 64];
    const int t    = threadIdx.x;
    const int wid  = t >> 6;
    const int lane = t & 63;
    const int lrow = lane & 15;
    const int lq   = lane >> 4;

    const int lid  = blockIdx.y * NBX + blockIdx.x;
    const int xcd  = lid & 7;
    const int slot = lid >> 3;
    const int by   = xcd * (gridDim.y >> 3) + slot / NBX;
    const int bx   = slot % NBX;
    const int m0   = by * 128;
    const int n0   = bx * 128;

    const int wm   = (wid >> 1) * 64;
    const int wn   = (wid & 1) * 64;

    f32x4 acc[4][4] = {};

    for (int k0 = 0; k0 < K; k0 += 64) {
#pragma unroll
        for (int p = 0; p < 4; p++) {
            const int c   = p * 256 + t;          // chunk 0..1023
            const int row = c >> 3;
            const int kb  = (c & 7) ^ (row & 7);  // un-swizzled global k-block
            async_ld16(A  + (size_t)(m0 + row) * K + k0 + kb * 8, (char*)As + c * 16);
            async_ld16(Bm + (size_t)(n0 + row) * K + k0 + kb * 8, (char*)Bs + c * 16);
        }
        __syncthreads();

#pragma unroll
        for (int ks = 0; ks < 2; ks++) {
            bf16_8 af[4], bfr[4];
#pragma unroll
            for (int mt = 0; mt < 4; mt++) {
                const int r  = wm + mt * 16 + lrow;
                const int kb = (ks * 4 + lq) ^ (r & 7);
                af[mt] = *(const bf16_8*)(As + (r * 8 + kb) * 8);
            }
#pragma unroll
            for (int nt = 0; nt < 4; nt++) {
                const int r  = wn + nt * 16 + lrow;
                const int kb = (ks * 4 + lq) ^ (r & 7);
                bfr[nt] = *(const bf16_8*)(Bs + (r * 8 + kb) * 8);
            }
#pragma unroll
            for (int mt = 0; mt < 4; mt++)
#pragma unroll
                for (int nt = 0; nt < 4; nt++)
                    acc[mt][nt] = __builtin_amdgcn_mfma_f32_16x16x32_bf16(af[mt], bfr[nt], acc[mt][nt], 0, 0, 0);
        }
        __syncthreads();
    }

#pragma unroll
    for (int nt = 0; nt < 4; nt++) {
        const int col = n0 + wn + nt * 16 + lrow;
        const float bv = bias[col];
#pragma unroll
        for (int mt = 0; mt < 4; mt++) {
            const int row = m0 + wm + mt * 16 + lq * 4;
            f32x4 a = acc[mt][nt];
            if (OUT_BF16) {
                unsigned short* Cp = (unsigned short*)C;
#pragma unroll
                for (int i = 0; i < 4; i++)
                    Cp[(size_t)(row + i) * N + col] = f2bf(a[i] + bv);
            } else {
                float* Cp = (float*)C;
#pragma unroll
                for (int i = 0; i < 4; i++)
                    Cp[(size_t)(row + i) * N + col] = a[i] + bv;
            }
        }
    }
}

// ---------------- gemm_bt2: 256x256 tile, 8-wave, 8-phase counted-vmcnt (GEMM1) ----
// Identical schedule to round 1 (refcheck-passed). Round-2 fixes:
//  - __launch_bounds__(512, 1): the (512,2) bound capped unified regs at 256
//    (= 128 arch VGPR + 128 AGPR acc, exactly the reported VGPR_Count) and
//    forced scratch spills (+35 MB WRITE_SIZE). LDS (128 KiB) already caps
//    occupancy at 1 block/CU = 8 waves, so the ,2 bound bought nothing.
//  - sched_barrier(0) after lgkmcnt(0) (rule #18: hipcc hoists reg-only MFMA
//    past inline-asm waitcnt).

#define LDA_H(AS, MH, AF) do {                                                     \
  _Pragma("unroll") for (int m_ = 0; m_ < 4; m_++)                                 \
  _Pragma("unroll") for (int ks_ = 0; ks_ < 2; ks_++) {                            \
    const int rho_ = (MH)*128 + wr*64 + m_*16 + lrow;                              \
    AF[m_][ks_] = *(const bf16_8*)((const u16*)(AS) + rho_*64 +                    \
                                   (((ks_*4+lq) ^ (lrow&7)) << 3)); } } while (0)

#define LDB_H(BS, NH, BF) do {                                                     \
  _Pragma("unroll") for (int n_ = 0; n_ < 2; n_++)                                 \
  _Pragma("unroll") for (int ks_ = 0; ks_ < 2; ks_++) {                            \
    const int rho_ = (NH)*128 + wc*32 + n_*16 + lrow;                              \
    BF[n_][ks_] = *(const bf16_8*)((const u16*)(BS) + rho_*64 +                    \
                                   (((ks_*4+lq) ^ (lrow&7)) << 3)); } } while (0)

#define MMA_Q(MH, NH, AF, BF) do {                                                 \
    __builtin_amdgcn_s_setprio(1);                                                 \
    _Pragma("unroll") for (int ks_ = 0; ks_ < 2; ks_++)                            \
    _Pragma("unroll") for (int m_ = 0; m_ < 4; m_++)                               \
    _Pragma("unroll") for (int n_ = 0; n_ < 2; n_++)                               \
        acc[(MH)*4+m_][(NH)*2+n_] = __builtin_amdgcn_mfma_f32_16x16x32_bf16(       \
            AF[m_][ks_], BF[n_][ks_], acc[(MH)*4+m_][(NH)*2+n_], 0, 0, 0);         \
    __builtin_amdgcn_s_setprio(0);                                                 \
  } while (0)

#define BAR()       __builtin_amdgcn_s_barrier()
#define WAIT_LGKM() do { asm volatile("s_waitcnt lgkmcnt(0)" ::: "memory");        \
                         __builtin_amdgcn_sched_barrier(0); } while (0)

template<int N, int NBX, int KK, bool OUT_BF16>
__global__ __launch_bounds__(512, 1)
void gemm_bt2(const u16* __restrict__ A, const u16* __restrict__ Bm,
              const float* __restrict__ bias, void* __restrict__ C) {
    __shared__ u16 As[2][256 * 64];
    __shared__ u16 Bs[2][256 * 64];

    const int t    = threadIdx.x;
    const int wid  = t >> 6;
    const int lane = t & 63;
    const int lrow = lane & 15;
    const int lq   = lane >> 4;
    const int wr   = wid >> 2;   // 0..1  (M wave row)
    const int wc   = wid & 3;    // 0..3  (N wave col)

    const int lid  = blockIdx.y * NBX + blockIdx.x;
    const int xcd  = lid & 7;
    const int slot = lid >> 3;
    const int by   = xcd * (gridDim.y >> 3) + slot / NBX;
    const int bx   = slot % NBX;
    const int m0   = by * 256;
    const int n0   = bx * 256;

    const u16* Ab = A  + (size_t)m0 * KK;
    const u16* Bb = Bm + (size_t)n0 * KK;

    f32x4 acc[8][4] = {};

    auto STG = [&](const u16* __restrict__ G, char* lds, int half, int k0, bool isA) {
#pragma unroll
        for (int cc = 0; cc < 2; cc++) {
            const int rho = half * 128 + cc * 64 + (t >> 3);
            const int blk = t & 7;
            const int g   = isA ? (((rho >> 6) & 1) * 128 + ((rho >> 7) & 1) * 64 + (rho & 63))
                                : (((rho >> 5) & 3) * 64  + ((rho >> 7) & 1) * 32 + (rho & 31));
            async_ld16(G + (size_t)g * KK + k0 + ((blk ^ (rho & 7)) << 3),
                       lds + rho * 128 + blk * 16);
        }
    };

    char* as0 = (char*)&As[0][0]; char* as1 = (char*)&As[1][0];
    char* bs0 = (char*)&Bs[0][0]; char* bs1 = (char*)&Bs[1][0];

    // prologue: tile0 fully into buf0; tile1's first 3 halves into buf1
    STG(Ab, as0, 0, 0,  true);
    STG(Bb, bs0, 0, 0,  false);
    STG(Bb, bs0, 1, 0,  false);
    STG(Ab, as0, 1, 0,  true);
    STG(Ab, as1, 0, 64, true);
    STG(Bb, bs1, 0, 64, false);
    STG(Bb, bs1, 1, 64, false);
    asm volatile("s_waitcnt vmcnt(6)" ::: "memory");   // tile0 landed
    BAR();

    bf16_8 af[4][2], blo[2][2], bhi[2][2];

    constexpr int NT = KK / 64;
    constexpr int NI = NT / 2;

    for (int i = 0; i < NI; ++i) {
        const bool pf = (i < NI - 1);
        const int kE = (2 * i + 2) * 64;
        const int kO = (2 * i + 3) * 64;

        // ---- P1: read E.A-lo + E.B-lo ; stage O.A-hi ; mma quad(0,0)
        LDA_H(as0, 0, af);
        LDB_H(bs0, 0, blo);
        STG(Ab, as1, 1, (2 * i + 1) * 64, true);
        BAR(); WAIT_LGKM();
        MMA_Q(0, 0, af, blo);
        BAR();
        // ---- P2: read E.B-hi ; stage E'.A-lo ; mma quad(0,1)
        LDB_H(bs0, 1, bhi);
        if (pf) STG(Ab, as0, 0, kE, true);
        BAR(); WAIT_LGKM();
        MMA_Q(0, 1, af, bhi);
        BAR();
        // ---- P3: read E.A-hi ; stage E'.B-lo ; mma quad(1,1)
        LDA_H(as0, 1, af);
        if (pf) STG(Bb, bs0, 0, kE, false);
        BAR(); WAIT_LGKM();
        MMA_Q(1, 1, af, bhi);
        BAR();
        // ---- P4: stage E'.B-hi ; mma quad(1,0) ; vmcnt -> tile O landed
        if (pf) STG(Bb, bs0, 1, kE, false);
        BAR();
        MMA_Q(1, 0, af, blo);
        if (pf) { asm volatile("s_waitcnt vmcnt(6)" ::: "memory"); }
        else    { asm volatile("s_waitcnt vmcnt(0)" ::: "memory"); }
        BAR();
        // ---- P5: read O.A-lo + O.B-lo ; stage E'.A-hi ; mma quad(0,0)
        LDA_H(as1, 0, af);
        LDB_H(bs1, 0, blo);
        if (pf) STG(Ab, as0, 1, kE, true);
        BAR(); WAIT_LGKM();
        MMA_Q(0, 0, af, blo);
        BAR();
        // ---- P6: read O.B-hi ; stage O'.A-lo ; mma quad(0,1)
        LDB_H(bs1, 1, bhi);
        if (pf) STG(Ab, as1, 0, kO, true);
        BAR(); WAIT_LGKM();
        MMA_Q(0, 1, af, bhi);
        BAR();
        // ---- P7: read O.A-hi ; stage O'.B-lo ; mma quad(1,1)
        LDA_H(as1, 1, af);
        if (pf) STG(Bb, bs1, 0, kO, false);
        BAR(); WAIT_LGKM();
        MMA_Q(1, 1, af, bhi);
        BAR();
        // ---- P8: stage O'.B-hi ; mma quad(1,0) ; vmcnt -> tile E' landed
        if (pf) STG(Bb, bs1, 1, kO, false);
        BAR();
        MMA_Q(1, 0, af, blo);
        if (pf) asm volatile("s_waitcnt vmcnt(6)" ::: "memory");
        BAR();
    }

    // epilogue: row = m0 + wr*128 + mt*16 + lq*4 + i, col = n0 + wc*64 + nt*16 + lrow
#pragma unroll
    for (int nt = 0; nt < 4; nt++) {
        const int col = n0 + wc * 64 + nt * 16 + lrow;
        const float bv = bias[col];
#pragma unroll
        for (int mt = 0; mt < 8; mt++) {
            const int row = m0 + wr * 128 + mt * 16 + lq * 4;
            f32x4 a = acc[mt][nt];
            if (OUT_BF16) {
                u16* Cp = (u16*)C;
#pragma unroll
                for (int i2 = 0; i2 < 4; i2++)
                    Cp[(size_t)(row + i2) * N + col] = f2bf(a[i2] + bv);
            } else {
                float* Cp = (float*)C;
#pragma unroll
                for (int i2 = 0; i2 < 4; i2++)
                    Cp[(size_t)(row + i2) * N + col] = a[i2] + bv;
            }
        }
    }
}

// ---------------- attention, stage 1: partial scores ----------------
__global__ __launch_bounds__(256)
void attn_scores(const unsigned short* __restrict__ Y, float* __restrict__ Scp) {
    __shared__ unsigned short Qs[64 * 72];
    __shared__ unsigned short Ks[64 * 72];
    const int bh = blockIdx.x, ch = blockIdx.y;
    const int b = bh >> 4, h = bh & 15;
    const size_t ybase = (size_t)b * S_ * 3072;
    const int qoff = h * 64, koff = D_ + h * 64;
    const int t = threadIdx.x, wid = t >> 6, lane = t & 63;
    const int lrow = lane & 15, lq = lane >> 4;

    f32x4 acc[4] = {};
    const int sbeg = ch * (S_ / NCH);
    for (int s0 = sbeg; s0 < sbeg + S_ / NCH; s0 += 64) {
#pragma unroll
        for (int p = 0; p < 4; p++) {
            int idx = p * 256 + t;            // 0..1023
            int r = idx >> 4, cg = (idx & 15) * 4;
            const size_t gb = ybase + (size_t)(s0 + r) * 3072;
            ushort4 q4 = *(const ushort4*)(Y + gb + qoff + cg);
            ushort4 k4 = *(const ushort4*)(Y + gb + koff + cg);
            Qs[(cg + 0) * 72 + r] = q4.x; Qs[(cg + 1) * 72 + r] = q4.y;
            Qs[(cg + 2) * 72 + r] = q4.z; Qs[(cg + 3) * 72 + r] = q4.w;
            Ks[(cg + 0) * 72 + r] = k4.x; Ks[(cg + 1) * 72 + r] = k4.y;
            Ks[(cg + 2) * 72 + r] = k4.z; Ks[(cg + 3) * 72 + r] = k4.w;
        }
        __syncthreads();
#pragma unroll
        for (int ks = 0; ks < 2; ks++) {
            bf16_8 aq = *(const bf16_8*)(Qs + (wid * 16 + lrow) * 72 + ks * 32 + lq * 8);
#pragma unroll
            for (int nt = 0; nt < 4; nt++) {
                bf16_8 bk = *(const bf16_8*)(Ks + (nt * 16 + lrow) * 72 + ks * 32 + lq * 8);
                acc[nt] = __builtin_amdgcn_mfma_f32_16x16x32_bf16(aq, bk, acc[nt], 0, 0, 0);
            }
        }
        __syncthreads();
    }

    float* out = Scp + (size_t)(bh * NCH + ch) * 64 * 64;
#pragma unroll
    for (int nt = 0; nt < 4; nt++)
#pragma unroll
        for (int i = 0; i < 4; i++)
            out[(wid * 16 + lq * 4 + i) * 64 + nt * 16 + lrow] = acc[nt][i];
}

// ---------------- attention, stage 2: reduce partials + softmax ----------------
__global__ __launch_bounds__(256)
void attn_softmax(const float* __restrict__ Scp, unsigned short* __restrict__ Wb) {
    const int bh = blockIdx.x;
    const int t = threadIdx.x;
    const int d = t >> 2, q = t & 3;
    float s[16] = {};
#pragma unroll
    for (int c = 0; c < NCH; c++) {
        const float4* p = (const float4*)(Scp + ((size_t)(bh * NCH + c) * 64 + d) * 64 + q * 16);
#pragma unroll
        for (int j = 0; j < 4; j++) {
            float4 v = p[j];
            s[j*4+0] += v.x; s[j*4+1] += v.y; s[j*4+2] += v.z; s[j*4+3] += v.w;
        }
    }
    const float scale = 0.022097086912079608f;  // 1/sqrt(2048)
    float m = -3.0e38f;
#pragma unroll
    for (int i = 0; i < 16; i++) { s[i] *= scale; m = fmaxf(m, s[i]); }
    m = fmaxf(m, __shfl_xor(m, 1));
    m = fmaxf(m, __shfl_xor(m, 2));
    float sum = 0.f;
#pragma unroll
    for (int i = 0; i < 16; i++) { s[i] = __expf(s[i] - m); sum += s[i]; }
    sum += __shfl_xor(sum, 1);
    sum += __shfl_xor(sum, 2);
    const float inv = 1.0f / sum;
    unsigned short* w = Wb + (size_t)bh * 4096 + d * 64 + q * 16;
    ushort4 o0, o1, o2, o3;
    o0.x=f2bf(s[0]*inv);  o0.y=f2bf(s[1]*inv);  o0.z=f2bf(s[2]*inv);  o0.w=f2bf(s[3]*inv);
    o1.x=f2bf(s[4]*inv);  o1.y=f2bf(s[5]*inv);  o1.z=f2bf(s[6]*inv);  o1.w=f2bf(s[7]*inv);
    o2.x=f2bf(s[8]*inv);  o2.y=f2bf(s[9]*inv);  o2.z=f2bf(s[10]*inv); o2.w=f2bf(s[11]*inv);
    o3.x=f2bf(s[12]*inv); o3.y=f2bf(s[13]*inv); o3.z=f2bf(s[14]*inv); o3.w=f2bf(s[15]*inv);
    ((ushort4*)w)[0]=o0; ((ushort4*)w)[1]=o1; ((ushort4*)w)[2]=o2; ((ushort4*)w)[3]=o3;
}

// ---------------- attention, stage 3: O = w @ V^T ----------------
__global__ __launch_bounds__(256)
void attn_out(const unsigned short* __restrict__ Y, const unsigned short* __restrict__ Wb,
              unsigned short* __restrict__ O) {
    __shared__ unsigned short Ws[64 * 72];
    const int bh = blockIdx.x, sc = blockIdx.y;
    const int b = bh >> 4, h = bh & 15;
    const size_t ybase = (size_t)b * S_ * 3072;
    const int voff = 2 * D_ + h * 64;
    const int t = threadIdx.x, wid = t >> 6, lane = t & 63;
    const int lrow = lane & 15, lq = lane >> 4;

    {
        const int d = t >> 2, q = t & 3;
        const uint4* src = (const uint4*)(Wb + (size_t)bh * 4096 + d * 64 + q * 16);
        uint4* dst = (uint4*)(Ws + d * 72 + q * 16);
        dst[0] = src[0];
        *(uint4*)(Ws + d * 72 + q * 16 + 8) = src[1];
    }
    __syncthreads();

    bf16_8 aw[4][2];
#pragma unroll
    for (int mt = 0; mt < 4; mt++)
#pragma unroll
        for (int ks = 0; ks < 2; ks++)
            aw[mt][ks] = *(const bf16_8*)(Ws + (mt * 16 + lrow) * 72 + ks * 32 + lq * 8);

    const size_t obase = (size_t)b * (H_ * DH_ * S_) + (size_t)h * (DH_ * S_);
    const int s0 = sc * 256 + wid * 64;
    f32x4 o[4][4] = {};
#pragma unroll
    for (int ks = 0; ks < 2; ks++) {
        bf16_8 bv[4];
#pragma unroll
        for (int nt = 0; nt < 4; nt++)
            bv[nt] = *(const bf16_8*)(Y + ybase + (size_t)(s0 + nt * 16 + lrow) * 3072 + voff + ks * 32 + lq * 8);
#pragma unroll
        for (int mt = 0; mt < 4; mt++)
#pragma unroll
            for (int nt = 0; nt < 4; nt++)
                o[mt][nt] = __builtin_amdgcn_mfma_f32_16x16x32_bf16(aw[mt][ks], bv[nt], o[mt][nt], 0, 0, 0);
    }
#pragma unroll
    for (int mt = 0; mt < 4; mt++)
#pragma unroll
        for (int nt = 0; nt < 4; nt++) {
            const int d = mt * 16 + lq * 4;
            const int s = s0 + nt * 16 + lrow;
#pragma unroll
            for (int i = 0; i < 4; i++)
                O[obase + (size_t)(d + i) * S_ + s] = f2bf(o[mt][nt][i]);
        }
}

extern "C" void kernel_launch(void* const* d_in, const int* in_sizes, int n_in,
                              void* d_out, int out_size, void* d_ws, size_t ws_size,
                              hipStream_t stream) {
    const float* X  = (const float*)d_in[0];
    const float* W1 = (const float*)d_in[1];
    const float* b1 = (const float*)d_in[2];
    const float* W2 = (const float*)d_in[3];
    const float* b2 = (const float*)d_in[4];

    char* ws = (char*)d_ws;
    unsigned short* Xb  = (unsigned short*)(ws + 0);                 // 16 MB, dead after GEMM1
    unsigned short* W1b = (unsigned short*)(ws + (16u << 20));       // 6 MB, dead after GEMM1
    unsigned short* W2b = (unsigned short*)(ws + (22u << 20));       // 2 MB
    unsigned short* Yb  = (unsigned short*)(ws + (24u << 20));       // 48 MB
    // after GEMM1, [0,22MB) is free:
    unsigned short* Wb  = (unsigned short*)(ws + 0);                 // 512 KB softmaxed weights
    unsigned short* Ob  = (unsigned short*)(ws + (1u << 20));        // 16 MB attention output
    // d_out (32 MB fp32) is dead until GEMM2 -> use 8 MB of it for score partials
    float* Scp = (float*)d_out;

    cast_kernel<<<12288, 256, 0, stream>>>(X, W1, W2, Xb, W1b, W2b);
    gemm_bt2<N1_, N1_/256, K_, true><<<dim3(N1_ / 256, M_TOT / 256), 512, 0, stream>>>(Xb, W1b, b1, Yb);
    attn_scores<<<dim3(64, NCH), 256, 0, stream>>>(Yb, Scp);
    attn_softmax<<<64, 256, 0, stream>>>(Scp, Wb);
    attn_out<<<dim3(64, NCH), 256, 0, stream>>>(Yb, Wb, Ob);
    gemm_bt<D_, D_/128, false><<<dim3(D_ / 128, M_TOT / 128), 256, 0, stream>>>(Ob, W2b, b2, d_out, K_);
}

// Round 3
// 210.587 us; speedup vs baseline: 1.0938x; 1.0539x over previous
//
#include <hip/hip_runtime.h>
#include <stdint.h>

#define B_ 4
#define S_ 2048
#define D_ 1024
#define H_ 16
#define DH_ 64
#define M_TOT (B_*S_)   // 8192
#define N1_ (3*D_)      // 3072
#define K_ D_           // 1024
#define NCH 8           // s-chunks for attention score partials

typedef __bf16 bf16_8 __attribute__((ext_vector_type(8)));
typedef float  f32x4  __attribute__((ext_vector_type(4)));
typedef unsigned short u16;

typedef __attribute__((address_space(1))) const void* gas_t;
typedef __attribute__((address_space(3))) void*       las_t;

__device__ __forceinline__ unsigned short f2bf(float f) {
    union { float f; unsigned u; } v; v.f = f;
    unsigned r = v.u + 0x7FFFu + ((v.u >> 16) & 1u);
    return (unsigned short)(r >> 16);
}

__device__ __forceinline__ void async_ld16(const void* g, void* l) {
    __builtin_amdgcn_global_load_lds((gas_t)g, (las_t)l, 16, 0, 0);
}

// ---------------- cast fp32 -> bf16 (X, W1, W2) ----------------
__global__ __launch_bounds__(256)
void cast_kernel(const float* __restrict__ X, const float* __restrict__ W1,
                 const float* __restrict__ W2, unsigned short* __restrict__ Xb,
                 unsigned short* __restrict__ W1b, unsigned short* __restrict__ W2b) {
    const int nX  = (M_TOT * K_) / 4;   // 2097152
    const int nW1 = (N1_ * K_) / 4;     // 786432
    int i = blockIdx.x * 256 + threadIdx.x;   // float4 index
    const float4* src; unsigned short* dst; int j;
    if (i < nX)            { src = (const float4*)X;  dst = Xb;  j = i; }
    else if (i < nX + nW1) { src = (const float4*)W1; dst = W1b; j = i - nX; }
    else                   { src = (const float4*)W2; dst = W2b; j = i - nX - nW1; }
    float4 v = src[j];
    ushort4 o;
    o.x = f2bf(v.x); o.y = f2bf(v.y); o.z = f2bf(v.z); o.w = f2bf(v.w);
    ((ushort4*)dst)[j] = o;
}

// ---------------- gemm_bt: C[M,N] = A[M,K] * B[N,K]^T + bias ----------------
// Round-0 proven kernel: 128x128 tile, 4 waves (2x2), BK=64, global_load_lds
// width 16, XOR-swizzled LDS (0 bank conflicts measured), XCD-aware swizzle.
// 73.4 us for GEMM1 (MfmaUtil 28%) = the m97-structure ceiling at this shape.
// The 256^2 8-phase experiment (rounds 1-2) lost to this on tail packing
// (384 blocks / 256 CUs) + lockstep LDS<->MFMA serialization; reverted.
template<int N, int NBX, bool OUT_BF16>
__global__ __launch_bounds__(256)
void gemm_bt(const unsigned short* __restrict__ A,
             const unsigned short* __restrict__ Bm,
             const float* __restrict__ bias,
             void* __restrict__ C, int K) {
    __shared__ unsigned short As[128 * 64];
    __shared__ unsigned short Bs[128 * 64];
    const int t    = threadIdx.x;
    const int wid  = t >> 6;
    const int lane = t & 63;
    const int lrow = lane & 15;
    const int lq   = lane >> 4;

    const int lid  = blockIdx.y * NBX + blockIdx.x;
    const int xcd  = lid & 7;
    const int slot = lid >> 3;
    const int by   = xcd * (gridDim.y >> 3) + slot / NBX;
    const int bx   = slot % NBX;
    const int m0   = by * 128;
    const int n0   = bx * 128;

    const int wm   = (wid >> 1) * 64;
    const int wn   = (wid & 1) * 64;

    f32x4 acc[4][4] = {};

    for (int k0 = 0; k0 < K; k0 += 64) {
#pragma unroll
        for (int p = 0; p < 4; p++) {
            const int c   = p * 256 + t;          // chunk 0..1023
            const int row = c >> 3;
            const int kb  = (c & 7) ^ (row & 7);  // un-swizzled global k-block
            async_ld16(A  + (size_t)(m0 + row) * K + k0 + kb * 8, (char*)As + c * 16);
            async_ld16(Bm + (size_t)(n0 + row) * K + k0 + kb * 8, (char*)Bs + c * 16);
        }
        __syncthreads();

#pragma unroll
        for (int ks = 0; ks < 2; ks++) {
            bf16_8 af[4], bfr[4];
#pragma unroll
            for (int mt = 0; mt < 4; mt++) {
                const int r  = wm + mt * 16 + lrow;
                const int kb = (ks * 4 + lq) ^ (r & 7);
                af[mt] = *(const bf16_8*)(As + (r * 8 + kb) * 8);
            }
#pragma unroll
            for (int nt = 0; nt < 4; nt++) {
                const int r  = wn + nt * 16 + lrow;
                const int kb = (ks * 4 + lq) ^ (r & 7);
                bfr[nt] = *(const bf16_8*)(Bs + (r * 8 + kb) * 8);
            }
#pragma unroll
            for (int mt = 0; mt < 4; mt++)
#pragma unroll
                for (int nt = 0; nt < 4; nt++)
                    acc[mt][nt] = __builtin_amdgcn_mfma_f32_16x16x32_bf16(af[mt], bfr[nt], acc[mt][nt], 0, 0, 0);
        }
        __syncthreads();
    }

    // epilogue: C row = m0+wm+mt*16+lq*4+i, col = n0+wn+nt*16+lrow
#pragma unroll
    for (int nt = 0; nt < 4; nt++) {
        const int col = n0 + wn + nt * 16 + lrow;
        const float bv = bias[col];
#pragma unroll
        for (int mt = 0; mt < 4; mt++) {
            const int row = m0 + wm + mt * 16 + lq * 4;
            f32x4 a = acc[mt][nt];
            if (OUT_BF16) {
                unsigned short* Cp = (unsigned short*)C;
#pragma unroll
                for (int i = 0; i < 4; i++)
                    Cp[(size_t)(row + i) * N + col] = f2bf(a[i] + bv);
            } else {
                float* Cp = (float*)C;
#pragma unroll
                for (int i = 0; i < 4; i++)
                    Cp[(size_t)(row + i) * N + col] = a[i] + bv;
            }
        }
    }
}

// ---------------- attention, stage 1: partial scores ----------------
// grid (bh=64, chunk=NCH). Each block: partial[d][e] = sum_{s in chunk} Q[s][d]K[s][e]
// stored fp32 at Scp[((bh*NCH+ch)*64+d)*64+e]
__global__ __launch_bounds__(256)
void attn_scores(const unsigned short* __restrict__ Y, float* __restrict__ Scp) {
    __shared__ unsigned short Qs[64 * 72];
    __shared__ unsigned short Ks[64 * 72];
    const int bh = blockIdx.x, ch = blockIdx.y;
    const int b = bh >> 4, h = bh & 15;
    const size_t ybase = (size_t)b * S_ * 3072;
    const int qoff = h * 64, koff = D_ + h * 64;
    const int t = threadIdx.x, wid = t >> 6, lane = t & 63;
    const int lrow = lane & 15, lq = lane >> 4;

    f32x4 acc[4] = {};
    const int sbeg = ch * (S_ / NCH);
    for (int s0 = sbeg; s0 < sbeg + S_ / NCH; s0 += 64) {
#pragma unroll
        for (int p = 0; p < 4; p++) {
            int idx = p * 256 + t;            // 0..1023
            int r = idx >> 4, cg = (idx & 15) * 4;
            const size_t gb = ybase + (size_t)(s0 + r) * 3072;
            ushort4 q4 = *(const ushort4*)(Y + gb + qoff + cg);
            ushort4 k4 = *(const ushort4*)(Y + gb + koff + cg);
            Qs[(cg + 0) * 72 + r] = q4.x; Qs[(cg + 1) * 72 + r] = q4.y;
            Qs[(cg + 2) * 72 + r] = q4.z; Qs[(cg + 3) * 72 + r] = q4.w;
            Ks[(cg + 0) * 72 + r] = k4.x; Ks[(cg + 1) * 72 + r] = k4.y;
            Ks[(cg + 2) * 72 + r] = k4.z; Ks[(cg + 3) * 72 + r] = k4.w;
        }
        __syncthreads();
#pragma unroll
        for (int ks = 0; ks < 2; ks++) {
            bf16_8 aq = *(const bf16_8*)(Qs + (wid * 16 + lrow) * 72 + ks * 32 + lq * 8);
#pragma unroll
            for (int nt = 0; nt < 4; nt++) {
                bf16_8 bk = *(const bf16_8*)(Ks + (nt * 16 + lrow) * 72 + ks * 32 + lq * 8);
                acc[nt] = __builtin_amdgcn_mfma_f32_16x16x32_bf16(aq, bk, acc[nt], 0, 0, 0);
            }
        }
        __syncthreads();
    }

    float* out = Scp + (size_t)(bh * NCH + ch) * 64 * 64;
#pragma unroll
    for (int nt = 0; nt < 4; nt++)
#pragma unroll
        for (int i = 0; i < 4; i++)
            out[(wid * 16 + lq * 4 + i) * 64 + nt * 16 + lrow] = acc[nt][i];
}

// ---------------- attention, stage 2 (fused): reduce + softmax + O = w @ V^T ----
// grid (bh=64, sc=8). Each block REDUNDANTLY reduces its head's 8 score
// partials (128 KB fp32 from L2/L3) and softmaxes in-register (deterministic
// -> all 8 sc-blocks agree bit-exactly), writes w into LDS, then computes its
// 256-column slice of O[b,h,d,s] = sum_e w[d][e] * V[s][e].
// Replaces the separate attn_softmax kernel + Wb global round-trip + 1 gap.
__global__ __launch_bounds__(256)
void attn_out_fused(const unsigned short* __restrict__ Y,
                    const float* __restrict__ Scp,
                    unsigned short* __restrict__ O) {
    __shared__ unsigned short Ws[64 * 72];
    const int bh = blockIdx.x, sc = blockIdx.y;
    const int b = bh >> 4, h = bh & 15;
    const size_t ybase = (size_t)b * S_ * 3072;
    const int voff = 2 * D_ + h * 64;
    const int t = threadIdx.x, wid = t >> 6, lane = t & 63;
    const int lrow = lane & 15, lq = lane >> 4;

    // --- reduce partials + softmax (thread t owns row d = t>>2, cols q*16..q*16+15)
    {
        const int d = t >> 2, q = t & 3;
        float s[16] = {};
#pragma unroll
        for (int c = 0; c < NCH; c++) {
            const float4* p = (const float4*)(Scp + ((size_t)(bh * NCH + c) * 64 + d) * 64 + q * 16);
#pragma unroll
            for (int j = 0; j < 4; j++) {
                float4 v = p[j];
                s[j*4+0] += v.x; s[j*4+1] += v.y; s[j*4+2] += v.z; s[j*4+3] += v.w;
            }
        }
        const float scale = 0.022097086912079608f;  // 1/sqrt(2048)
        float m = -3.0e38f;
#pragma unroll
        for (int i = 0; i < 16; i++) { s[i] *= scale; m = fmaxf(m, s[i]); }
        m = fmaxf(m, __shfl_xor(m, 1));   // 4-lane group = one row d
        m = fmaxf(m, __shfl_xor(m, 2));
        float sum = 0.f;
#pragma unroll
        for (int i = 0; i < 16; i++) { s[i] = __expf(s[i] - m); sum += s[i]; }
        sum += __shfl_xor(sum, 1);
        sum += __shfl_xor(sum, 2);
        const float inv = 1.0f / sum;
        unsigned short* w = Ws + d * 72 + q * 16;
#pragma unroll
        for (int i = 0; i < 16; i++) w[i] = f2bf(s[i] * inv);
    }
    __syncthreads();

    bf16_8 aw[4][2];
#pragma unroll
    for (int mt = 0; mt < 4; mt++)
#pragma unroll
        for (int ks = 0; ks < 2; ks++)
            aw[mt][ks] = *(const bf16_8*)(Ws + (mt * 16 + lrow) * 72 + ks * 32 + lq * 8);

    const size_t obase = (size_t)b * (H_ * DH_ * S_) + (size_t)h * (DH_ * S_);
    const int s0 = sc * 256 + wid * 64;
    f32x4 o[4][4] = {};
#pragma unroll
    for (int ks = 0; ks < 2; ks++) {
        bf16_8 bv[4];
#pragma unroll
        for (int nt = 0; nt < 4; nt++)
            bv[nt] = *(const bf16_8*)(Y + ybase + (size_t)(s0 + nt * 16 + lrow) * 3072 + voff + ks * 32 + lq * 8);
#pragma unroll
        for (int mt = 0; mt < 4; mt++)
#pragma unroll
            for (int nt = 0; nt < 4; nt++)
                o[mt][nt] = __builtin_amdgcn_mfma_f32_16x16x32_bf16(aw[mt][ks], bv[nt], o[mt][nt], 0, 0, 0);
    }
#pragma unroll
    for (int mt = 0; mt < 4; mt++)
#pragma unroll
        for (int nt = 0; nt < 4; nt++) {
            const int d = mt * 16 + lq * 4;
            const int s = s0 + nt * 16 + lrow;
#pragma unroll
            for (int i = 0; i < 4; i++)
                O[obase + (size_t)(d + i) * S_ + s] = f2bf(o[mt][nt][i]);
        }
}

extern "C" void kernel_launch(void* const* d_in, const int* in_sizes, int n_in,
                              void* d_out, int out_size, void* d_ws, size_t ws_size,
                              hipStream_t stream) {
    const float* X  = (const float*)d_in[0];
    const float* W1 = (const float*)d_in[1];
    const float* b1 = (const float*)d_in[2];
    const float* W2 = (const float*)d_in[3];
    const float* b2 = (const float*)d_in[4];

    char* ws = (char*)d_ws;
    unsigned short* Xb  = (unsigned short*)(ws + 0);                 // 16 MB, dead after GEMM1
    unsigned short* W1b = (unsigned short*)(ws + (16u << 20));       // 6 MB, dead after GEMM1
    unsigned short* W2b = (unsigned short*)(ws + (22u << 20));       // 2 MB
    unsigned short* Yb  = (unsigned short*)(ws + (24u << 20));       // 48 MB
    // after GEMM1, [0,22MB) is free:
    unsigned short* Ob  = (unsigned short*)(ws + (1u << 20));        // 16 MB attention output
    // d_out (32 MB fp32) is dead until GEMM2 -> use 8 MB of it for score partials
    float* Scp = (float*)d_out;

    cast_kernel<<<12288, 256, 0, stream>>>(X, W1, W2, Xb, W1b, W2b);
    gemm_bt<N1_, N1_/128, true><<<dim3(N1_ / 128, M_TOT / 128), 256, 0, stream>>>(Xb, W1b, b1, Yb, K_);
    attn_scores<<<dim3(64, NCH), 256, 0, stream>>>(Yb, Scp);
    attn_out_fused<<<dim3(64, NCH), 256, 0, stream>>>(Yb, Scp, Ob);
    gemm_bt<D_, D_/128, false><<<dim3(D_ / 128, M_TOT / 128), 256, 0, stream>>>(Ob, W2b, b2, d_out, K_);
}